// Round 4
// baseline (60.844 us; speedup 1.0000x reference)
//
#include <hip/hip_runtime.h>

#define T_STEPS 128
#define H 512
#define W 512
#define PLANE (H * W)

typedef float f4 __attribute__((ext_vector_type(4)));

// Four pixels (w0..w0+3) per thread via float4 loads/stores. LIF state in
// registers across the 128-step scan; 5-tap cross conv on the fly.
// Depth-2 software pipeline: while computing step t, planes t+1 and t+2 are
// in flight (issue t+2's loads before t's compute; wait only on t's slot).
__global__ __launch_bounds__(256) void lif_conv_scan(const float* __restrict__ x,
                                                     const float* __restrict__ k,
                                                     float* __restrict__ out) {
    const int q = blockIdx.x * 64 + threadIdx.x;   // quad index 0..127
    const int w0 = q * 4;                          // first pixel column
    const int h = blockIdx.y * 4 + threadIdx.y;    // 0..511
    const int idx = h * W + w0;

    const float kU = k[1], kL = k[3], kC = k[4], kR = k[5], kD = k[7];

    // clamped neighbor offsets + zeroed weights at borders (exact: acc + 0*x == acc)
    const int offU = (h > 0)      ? idx - W : idx;
    const int offD = (h < H - 1)  ? idx + W : idx;
    const float wU = (h > 0)      ? kU : 0.0f;
    const float wD = (h < H - 1)  ? kD : 0.0f;
    const int offL = (w0 > 0)     ? idx - 1 : idx;   // left neighbor of pixel 0
    const int offR = (w0 < W - 4) ? idx + 4 : idx;   // right neighbor of pixel 3
    const float wL = (w0 > 0)     ? kL : 0.0f;
    const float wR = (w0 < W - 4) ? kR : 0.0f;

    float v[4] = {0.0f, 0.0f, 0.0f, 0.0f};
    float cur[4] = {0.0f, 0.0f, 0.0f, 0.0f};

    // double-buffered pipeline slots (indices static via unroll 2)
    f4 C[2], U[2], D[2];
    float L[2], R[2];

    // preload planes 0 and 1
    C[0] = *(const f4*)(x + idx);
    U[0] = *(const f4*)(x + offU);
    D[0] = *(const f4*)(x + offD);
    L[0] = x[offL];
    R[0] = x[offR];
    C[1] = *(const f4*)(x + PLANE + idx);
    U[1] = *(const f4*)(x + PLANE + offU);
    D[1] = *(const f4*)(x + PLANE + offD);
    L[1] = x[PLANE + offL];
    R[1] = x[PLANE + offR];

    float* op = out + idx;

    #pragma unroll 2
    for (int t = 0; t < T_STEPS; ++t) {
        const int s = t & 1;

        // issue plane t+2's loads now (clamped dummy on the last two iters)
        const float* xf = x + (size_t)((t + 2 < T_STEPS) ? (t + 2) : t) * PLANE;
        const f4 nC = *(const f4*)(xf + idx);
        const f4 nU = *(const f4*)(xf + offU);
        const f4 nD = *(const f4*)(xf + offD);
        const float nL = xf[offL];
        const float nR = xf[offR];

        // compute step t from slot s
        const f4 c = C[s], u = U[s], d = D[s];
        const float lf = L[s], rt = R[s];

        float cv[4];
        cv[0] = wU * u.x; cv[0] += wL * lf;  cv[0] += kC * c.x; cv[0] += kR * c.y; cv[0] += wD * d.x;
        cv[1] = wU * u.y; cv[1] += kL * c.x; cv[1] += kC * c.y; cv[1] += kR * c.z; cv[1] += wD * d.y;
        cv[2] = wU * u.z; cv[2] += kL * c.y; cv[2] += kC * c.z; cv[2] += kR * c.w; cv[2] += wD * d.z;
        cv[3] = wU * u.w; cv[3] += kL * c.z; cv[3] += kC * c.w; cv[3] += wR * rt;  cv[3] += wD * d.w;

        f4 z;
        #pragma unroll
        for (int j = 0; j < 4; ++j) {
            const float vd = v[j] + 0.2f * (cur[j] - v[j]);
            const bool sp = (vd - 1.0f) > 0.0f;
            z[j] = sp ? 1.0f : 0.0f;
            v[j] = sp ? 0.0f : vd;
            cur[j] = cur[j] * 0.8f + cv[j];
        }
        __builtin_nontemporal_store(z, (f4*)op);
        op += PLANE;

        // rotate: slot s now holds plane t+2
        C[s] = nC; U[s] = nU; D[s] = nD; L[s] = nL; R[s] = nR;
    }
}

extern "C" void kernel_launch(void* const* d_in, const int* in_sizes, int n_in,
                              void* d_out, int out_size, void* d_ws, size_t ws_size,
                              hipStream_t stream) {
    const float* x = (const float*)d_in[0];
    const float* k = (const float*)d_in[1];
    float* out = (float*)d_out;

    dim3 block(64, 4);
    dim3 grid(W / 256, H / 4);   // 2 x 128 = 256 blocks, 1 per CU
    lif_conv_scan<<<grid, block, 0, stream>>>(x, k, out);
}

// Round 5
// 55.820 us; speedup vs baseline: 1.0900x; 1.0900x over previous
//
#include <hip/hip_runtime.h>

#define T_STEPS 128
#define H 512
#define W 512
#define PLANE (H * W)

typedef float f2 __attribute__((ext_vector_type(2)));

// Two pixels (w0, w0+1) per thread. LIF state in registers across the
// 128-step scan; 5-tap cross conv on the fly. Depth-2 software pipeline:
// while computing step t, planes t+1 AND t+2 are in flight (~32 KB/CU
// outstanding at 8 waves/CU — 3.5x the Little's-law requirement).
__global__ __launch_bounds__(256) void lif_conv_scan(const float* __restrict__ x,
                                                     const float* __restrict__ k,
                                                     float* __restrict__ out) {
    const int wpair = blockIdx.x * 64 + threadIdx.x;   // 0..255
    const int w0 = wpair * 2;                          // even pixel column
    const int h = blockIdx.y * 4 + threadIdx.y;        // 0..511
    const int idx = h * W + w0;

    const float kU = k[1], kL = k[3], kC = k[4], kR = k[5], kD = k[7];

    // clamped neighbor offsets + zeroed weights at borders (exact: acc + 0*x == acc)
    const int offU = (h > 0)      ? idx - W : idx;
    const int offD = (h < H - 1)  ? idx + W : idx;
    const float wU = (h > 0)      ? kU : 0.0f;
    const float wD = (h < H - 1)  ? kD : 0.0f;
    const int offL = (w0 > 0)     ? idx - 1 : idx;     // left neighbor of p0
    const int offR = (w0 < W - 2) ? idx + 2 : idx;     // right neighbor of p1
    const float wL = (w0 > 0)     ? kL : 0.0f;
    const float wR = (w0 < W - 2) ? kR : 0.0f;

    float v0 = 0.0f, v1 = 0.0f, i0 = 0.0f, i1 = 0.0f;

    // double-buffered pipeline slots (indices static via unroll 2)
    f2 C[2], U[2], D[2];
    float L[2], R[2];

    // preload planes 0 and 1
    C[0] = *(const f2*)(x + idx);
    U[0] = *(const f2*)(x + offU);
    D[0] = *(const f2*)(x + offD);
    L[0] = x[offL];
    R[0] = x[offR];
    C[1] = *(const f2*)(x + PLANE + idx);
    U[1] = *(const f2*)(x + PLANE + offU);
    D[1] = *(const f2*)(x + PLANE + offD);
    L[1] = x[PLANE + offL];
    R[1] = x[PLANE + offR];

    float* op = out + idx;

    #pragma unroll 2
    for (int t = 0; t < T_STEPS; ++t) {
        const int s = t & 1;

        // issue plane t+2's loads now (clamped dummy on the last two iters)
        const float* xf = x + (size_t)((t + 2 < T_STEPS) ? (t + 2) : t) * PLANE;
        const f2 nC = *(const f2*)(xf + idx);
        const f2 nU = *(const f2*)(xf + offU);
        const f2 nD = *(const f2*)(xf + offD);
        const float nL = xf[offL];
        const float nR = xf[offR];

        // compute step t from slot s — same accumulation order as verified kernels
        const f2 c = C[s], u = U[s], d = D[s];
        const float lf = L[s], rt = R[s];

        float c0 = wU * u.x;
        c0 += wL * lf;
        c0 += kC * c.x;
        c0 += kR * c.y;
        c0 += wD * d.x;

        float c1 = wU * u.y;
        c1 += kL * c.x;
        c1 += kC * c.y;
        c1 += wR * rt;
        c1 += wD * d.y;

        const float vd0 = v0 + 0.2f * (i0 - v0);
        const bool s0 = (vd0 - 1.0f) > 0.0f;
        const float z0 = s0 ? 1.0f : 0.0f;
        v0 = s0 ? 0.0f : vd0;
        i0 = i0 * 0.8f + c0;

        const float vd1 = v1 + 0.2f * (i1 - v1);
        const bool s1 = (vd1 - 1.0f) > 0.0f;
        const float z1 = s1 ? 1.0f : 0.0f;
        v1 = s1 ? 0.0f : vd1;
        i1 = i1 * 0.8f + c1;

        f2 z;
        z.x = z0;
        z.y = z1;
        __builtin_nontemporal_store(z, (f2*)op);
        op += PLANE;

        // rotate: slot s now holds plane t+2
        C[s] = nC; U[s] = nU; D[s] = nD; L[s] = nL; R[s] = nR;
    }
}

extern "C" void kernel_launch(void* const* d_in, const int* in_sizes, int n_in,
                              void* d_out, int out_size, void* d_ws, size_t ws_size,
                              hipStream_t stream) {
    const float* x = (const float*)d_in[0];
    const float* k = (const float*)d_in[1];
    float* out = (float*)d_out;

    dim3 block(64, 4);
    dim3 grid(W / 128, H / 4);   // 4 x 128 = 512 blocks, 2 per CU
    lif_conv_scan<<<grid, block, 0, stream>>>(x, k, out);
}

// Round 6
// 54.531 us; speedup vs baseline: 1.1158x; 1.0236x over previous
//
#include <hip/hip_runtime.h>

#define T_STEPS 128
#define H 512
#define W 512
#define PLANE (H * W)

typedef float f2 __attribute__((ext_vector_type(2)));

// R5 kernel with ONE change: plain store instead of __builtin_nontemporal_store
// (A/B of the nt flag on the write stream).
__global__ __launch_bounds__(256) void lif_conv_scan(const float* __restrict__ x,
                                                     const float* __restrict__ k,
                                                     float* __restrict__ out) {
    const int wpair = blockIdx.x * 64 + threadIdx.x;   // 0..255
    const int w0 = wpair * 2;                          // even pixel column
    const int h = blockIdx.y * 4 + threadIdx.y;        // 0..511
    const int idx = h * W + w0;

    const float kU = k[1], kL = k[3], kC = k[4], kR = k[5], kD = k[7];

    // clamped neighbor offsets + zeroed weights at borders (exact: acc + 0*x == acc)
    const int offU = (h > 0)      ? idx - W : idx;
    const int offD = (h < H - 1)  ? idx + W : idx;
    const float wU = (h > 0)      ? kU : 0.0f;
    const float wD = (h < H - 1)  ? kD : 0.0f;
    const int offL = (w0 > 0)     ? idx - 1 : idx;     // left neighbor of p0
    const int offR = (w0 < W - 2) ? idx + 2 : idx;     // right neighbor of p1
    const float wL = (w0 > 0)     ? kL : 0.0f;
    const float wR = (w0 < W - 2) ? kR : 0.0f;

    float v0 = 0.0f, v1 = 0.0f, i0 = 0.0f, i1 = 0.0f;

    // double-buffered pipeline slots (indices static via unroll 2)
    f2 C[2], U[2], D[2];
    float L[2], R[2];

    // preload planes 0 and 1
    C[0] = *(const f2*)(x + idx);
    U[0] = *(const f2*)(x + offU);
    D[0] = *(const f2*)(x + offD);
    L[0] = x[offL];
    R[0] = x[offR];
    C[1] = *(const f2*)(x + PLANE + idx);
    U[1] = *(const f2*)(x + PLANE + offU);
    D[1] = *(const f2*)(x + PLANE + offD);
    L[1] = x[PLANE + offL];
    R[1] = x[PLANE + offR];

    float* op = out + idx;

    #pragma unroll 2
    for (int t = 0; t < T_STEPS; ++t) {
        const int s = t & 1;

        // issue plane t+2's loads now (clamped dummy on the last two iters)
        const float* xf = x + (size_t)((t + 2 < T_STEPS) ? (t + 2) : t) * PLANE;
        const f2 nC = *(const f2*)(xf + idx);
        const f2 nU = *(const f2*)(xf + offU);
        const f2 nD = *(const f2*)(xf + offD);
        const float nL = xf[offL];
        const float nR = xf[offR];

        // compute step t from slot s — same accumulation order as verified kernels
        const f2 c = C[s], u = U[s], d = D[s];
        const float lf = L[s], rt = R[s];

        float c0 = wU * u.x;
        c0 += wL * lf;
        c0 += kC * c.x;
        c0 += kR * c.y;
        c0 += wD * d.x;

        float c1 = wU * u.y;
        c1 += kL * c.x;
        c1 += kC * c.y;
        c1 += wR * rt;
        c1 += wD * d.y;

        const float vd0 = v0 + 0.2f * (i0 - v0);
        const bool s0 = (vd0 - 1.0f) > 0.0f;
        const float z0 = s0 ? 1.0f : 0.0f;
        v0 = s0 ? 0.0f : vd0;
        i0 = i0 * 0.8f + c0;

        const float vd1 = v1 + 0.2f * (i1 - v1);
        const bool s1 = (vd1 - 1.0f) > 0.0f;
        const float z1 = s1 ? 1.0f : 0.0f;
        v1 = s1 ? 0.0f : vd1;
        i1 = i1 * 0.8f + c1;

        f2 z;
        z.x = z0;
        z.y = z1;
        *(f2*)op = z;              // plain store (A/B vs nontemporal)
        op += PLANE;

        // rotate: slot s now holds plane t+2
        C[s] = nC; U[s] = nU; D[s] = nD; L[s] = nL; R[s] = nR;
    }
}

extern "C" void kernel_launch(void* const* d_in, const int* in_sizes, int n_in,
                              void* d_out, int out_size, void* d_ws, size_t ws_size,
                              hipStream_t stream) {
    const float* x = (const float*)d_in[0];
    const float* k = (const float*)d_in[1];
    float* out = (float*)d_out;

    dim3 block(64, 4);
    dim3 grid(W / 128, H / 4);   // 4 x 128 = 512 blocks, 2 per CU
    lif_conv_scan<<<grid, block, 0, stream>>>(x, k, out);
}

// Round 7
// 50.761 us; speedup vs baseline: 1.1986x; 1.0743x over previous
//
#include <hip/hip_runtime.h>

#define T_STEPS 128
#define H 512
#define W 512
#define PLANE (H * W)

typedef float f2 __attribute__((ext_vector_type(2)));

// 2 px/thread, depth-2 pipeline, plain stores (R6 winner), plus:
//  - lf/rt via __shfl from the center loads (edge lanes 0/63 do 1-lane loads)
//  - XCD-chunked block swizzle: each XCD owns 64 contiguous image rows so
//    vertical halo reuse is same-XCD L2 traffic instead of cross-XCD L3.
__global__ __launch_bounds__(256) void lif_conv_scan(const float* __restrict__ x,
                                                     const float* __restrict__ k,
                                                     float* __restrict__ out) {
    // bijective XCD swizzle: 512 blocks, 8 XCDs, 64 blocks per XCD chunk
    const int b = blockIdx.x;                 // 0..511, consecutive -> round-robin XCD
    const int logical = (b & 7) * 64 + (b >> 3);
    const int bx = logical & 3;               // 0..3   (w chunks of 128 px)
    const int by = logical >> 2;              // 0..127 (h chunks of 4 rows)

    const int tx = threadIdx.x;               // lane 0..63 (wave = one row segment)
    const int w0 = (bx * 64 + tx) * 2;        // even pixel column
    const int h = by * 4 + threadIdx.y;       // 0..511
    const int idx = h * W + w0;

    const float kU = k[1], kL = k[3], kC = k[4], kR = k[5], kD = k[7];

    const int offU = (h > 0)      ? idx - W : idx;
    const int offD = (h < H - 1)  ? idx + W : idx;
    const float wU = (h > 0)      ? kU : 0.0f;
    const float wD = (h < H - 1)  ? kD : 0.0f;
    const int offL = (w0 > 0)     ? idx - 1 : idx;     // used by lane 0 only
    const int offR = (w0 < W - 2) ? idx + 2 : idx;     // used by lane 63 only
    const float wL = (w0 > 0)     ? kL : 0.0f;
    const float wR = (w0 < W - 2) ? kR : 0.0f;

    float v0 = 0.0f, v1 = 0.0f, i0 = 0.0f, i1 = 0.0f;

    // double-buffered pipeline slots (indices static via unroll 2)
    f2 C[2], U[2], D[2];
    float L[2] = {0.0f, 0.0f}, R[2] = {0.0f, 0.0f};

    C[0] = *(const f2*)(x + idx);
    U[0] = *(const f2*)(x + offU);
    D[0] = *(const f2*)(x + offD);
    C[1] = *(const f2*)(x + PLANE + idx);
    U[1] = *(const f2*)(x + PLANE + offU);
    D[1] = *(const f2*)(x + PLANE + offD);
    if (tx == 0)  { L[0] = x[offL]; L[1] = x[PLANE + offL]; }
    if (tx == 63) { R[0] = x[offR]; R[1] = x[PLANE + offR]; }

    float* op = out + idx;

    #pragma unroll 2
    for (int t = 0; t < T_STEPS; ++t) {
        const int s = t & 1;

        // issue plane t+2's loads now (clamped dummy on the last two iters)
        const float* xf = x + (size_t)((t + 2 < T_STEPS) ? (t + 2) : t) * PLANE;
        const f2 nC = *(const f2*)(xf + idx);
        const f2 nU = *(const f2*)(xf + offU);
        const f2 nD = *(const f2*)(xf + offD);
        float nL = 0.0f, nR = 0.0f;
        if (tx == 0)  nL = xf[offL];
        if (tx == 63) nR = xf[offR];

        // compute step t from slot s
        const f2 c = C[s], u = U[s], d = D[s];
        float lf = __shfl_up(c.y, 1);           // lane l-1's right pixel = x[idx-1]
        lf = (tx == 0) ? L[s] : lf;
        float rt = __shfl_down(c.x, 1);         // lane l+1's left pixel = x[idx+2]
        rt = (tx == 63) ? R[s] : rt;

        // conv — same accumulation order as verified kernels
        float c0 = wU * u.x;
        c0 += wL * lf;
        c0 += kC * c.x;
        c0 += kR * c.y;
        c0 += wD * d.x;

        float c1 = wU * u.y;
        c1 += kL * c.x;
        c1 += kC * c.y;
        c1 += wR * rt;
        c1 += wD * d.y;

        const float vd0 = v0 + 0.2f * (i0 - v0);
        const bool s0 = (vd0 - 1.0f) > 0.0f;
        const float z0 = s0 ? 1.0f : 0.0f;
        v0 = s0 ? 0.0f : vd0;
        i0 = i0 * 0.8f + c0;

        const float vd1 = v1 + 0.2f * (i1 - v1);
        const bool s1 = (vd1 - 1.0f) > 0.0f;
        const float z1 = s1 ? 1.0f : 0.0f;
        v1 = s1 ? 0.0f : vd1;
        i1 = i1 * 0.8f + c1;

        f2 z;
        z.x = z0;
        z.y = z1;
        *(f2*)op = z;
        op += PLANE;

        // rotate: slot s now holds plane t+2
        C[s] = nC; U[s] = nU; D[s] = nD; L[s] = nL; R[s] = nR;
    }
}

extern "C" void kernel_launch(void* const* d_in, const int* in_sizes, int n_in,
                              void* d_out, int out_size, void* d_ws, size_t ws_size,
                              hipStream_t stream) {
    const float* x = (const float*)d_in[0];
    const float* k = (const float*)d_in[1];
    float* out = (float*)d_out;

    dim3 block(64, 4);
    dim3 grid(512);              // 1D; kernel swizzles to (bx, by)
    lif_conv_scan<<<grid, block, 0, stream>>>(x, k, out);
}

// Round 8
// 50.255 us; speedup vs baseline: 1.2107x; 1.0101x over previous
//
#include <hip/hip_runtime.h>

#define T_STEPS 128
#define H 512
#define W 512
#define PLANE (H * W)

typedef float f2 __attribute__((ext_vector_type(2)));

// R7 kernel with ONE change: nontemporal store (A/B in the L3-retention
// regime that the XCD swizzle created — protect x's residency in Infinity
// Cache from the dead-on-arrival output write stream).
__global__ __launch_bounds__(256) void lif_conv_scan(const float* __restrict__ x,
                                                     const float* __restrict__ k,
                                                     float* __restrict__ out) {
    // bijective XCD swizzle: 512 blocks, 8 XCDs, 64 blocks per XCD chunk
    const int b = blockIdx.x;                 // 0..511, consecutive -> round-robin XCD
    const int logical = (b & 7) * 64 + (b >> 3);
    const int bx = logical & 3;               // 0..3   (w chunks of 128 px)
    const int by = logical >> 2;              // 0..127 (h chunks of 4 rows)

    const int tx = threadIdx.x;               // lane 0..63 (wave = one row segment)
    const int w0 = (bx * 64 + tx) * 2;        // even pixel column
    const int h = by * 4 + threadIdx.y;       // 0..511
    const int idx = h * W + w0;

    const float kU = k[1], kL = k[3], kC = k[4], kR = k[5], kD = k[7];

    const int offU = (h > 0)      ? idx - W : idx;
    const int offD = (h < H - 1)  ? idx + W : idx;
    const float wU = (h > 0)      ? kU : 0.0f;
    const float wD = (h < H - 1)  ? kD : 0.0f;
    const int offL = (w0 > 0)     ? idx - 1 : idx;     // used by lane 0 only
    const int offR = (w0 < W - 2) ? idx + 2 : idx;     // used by lane 63 only
    const float wL = (w0 > 0)     ? kL : 0.0f;
    const float wR = (w0 < W - 2) ? kR : 0.0f;

    float v0 = 0.0f, v1 = 0.0f, i0 = 0.0f, i1 = 0.0f;

    // double-buffered pipeline slots (indices static via unroll 2)
    f2 C[2], U[2], D[2];
    float L[2] = {0.0f, 0.0f}, R[2] = {0.0f, 0.0f};

    C[0] = *(const f2*)(x + idx);
    U[0] = *(const f2*)(x + offU);
    D[0] = *(const f2*)(x + offD);
    C[1] = *(const f2*)(x + PLANE + idx);
    U[1] = *(const f2*)(x + PLANE + offU);
    D[1] = *(const f2*)(x + PLANE + offD);
    if (tx == 0)  { L[0] = x[offL]; L[1] = x[PLANE + offL]; }
    if (tx == 63) { R[0] = x[offR]; R[1] = x[PLANE + offR]; }

    float* op = out + idx;

    #pragma unroll 2
    for (int t = 0; t < T_STEPS; ++t) {
        const int s = t & 1;

        // issue plane t+2's loads now (clamped dummy on the last two iters)
        const float* xf = x + (size_t)((t + 2 < T_STEPS) ? (t + 2) : t) * PLANE;
        const f2 nC = *(const f2*)(xf + idx);
        const f2 nU = *(const f2*)(xf + offU);
        const f2 nD = *(const f2*)(xf + offD);
        float nL = 0.0f, nR = 0.0f;
        if (tx == 0)  nL = xf[offL];
        if (tx == 63) nR = xf[offR];

        // compute step t from slot s
        const f2 c = C[s], u = U[s], d = D[s];
        float lf = __shfl_up(c.y, 1);           // lane l-1's right pixel = x[idx-1]
        lf = (tx == 0) ? L[s] : lf;
        float rt = __shfl_down(c.x, 1);         // lane l+1's left pixel = x[idx+2]
        rt = (tx == 63) ? R[s] : rt;

        // conv — same accumulation order as verified kernels
        float c0 = wU * u.x;
        c0 += wL * lf;
        c0 += kC * c.x;
        c0 += kR * c.y;
        c0 += wD * d.x;

        float c1 = wU * u.y;
        c1 += kL * c.x;
        c1 += kC * c.y;
        c1 += wR * rt;
        c1 += wD * d.y;

        const float vd0 = v0 + 0.2f * (i0 - v0);
        const bool s0 = (vd0 - 1.0f) > 0.0f;
        const float z0 = s0 ? 1.0f : 0.0f;
        v0 = s0 ? 0.0f : vd0;
        i0 = i0 * 0.8f + c0;

        const float vd1 = v1 + 0.2f * (i1 - v1);
        const bool s1 = (vd1 - 1.0f) > 0.0f;
        const float z1 = s1 ? 1.0f : 0.0f;
        v1 = s1 ? 0.0f : vd1;
        i1 = i1 * 0.8f + c1;

        f2 z;
        z.x = z0;
        z.y = z1;
        __builtin_nontemporal_store(z, (f2*)op);   // A/B: stream the output past L3
        op += PLANE;

        // rotate: slot s now holds plane t+2
        C[s] = nC; U[s] = nU; D[s] = nD; L[s] = nL; R[s] = nR;
    }
}

extern "C" void kernel_launch(void* const* d_in, const int* in_sizes, int n_in,
                              void* d_out, int out_size, void* d_ws, size_t ws_size,
                              hipStream_t stream) {
    const float* x = (const float*)d_in[0];
    const float* k = (const float*)d_in[1];
    float* out = (float*)d_out;

    dim3 block(64, 4);
    dim3 grid(512);              // 1D; kernel swizzles to (bx, by)
    lif_conv_scan<<<grid, block, 0, stream>>>(x, k, out);
}